// Round 2
// baseline (199.703 us; speedup 1.0000x reference)
//
#include <hip/hip_runtime.h>
#include <math.h>

// Problem constants (B hard-coded to 8, C==1, H=W=2048 per reference)
constexpr int HH   = 2048;
constexpr int WW   = 2048;
constexpr int BB   = 8;
constexpr unsigned NPB  = (unsigned)HH * (unsigned)WW;  // 4,194,304 elements/batch
constexpr unsigned NVEC = NPB / 4;                       // 1,048,576 float4 per batch
constexpr int NBLK = 256;   // blocks per batch in pass 1
constexpr int TPB  = 256;
constexpr unsigned STRIDE = (unsigned)(NBLK * TPB);      // 65,536 float4
constexpr int NITER = (int)(NVEC / STRIDE);              // exactly 16

__device__ __forceinline__ void argmax_combine(float& bv, unsigned& bi,
                                               float ov, unsigned oi) {
    // jnp.argmax tie-break: smallest flat index wins
    if (ov > bv || (ov == bv && oi < bi)) { bv = ov; bi = oi; }
}

// Pass 1: per-(batch, block) partials over ALL elements:
//   max + argmax, sum(relu(x)), sum(relu(x)^2), count(x>0)
__global__ __launch_bounds__(TPB) void psr_pass1(
    const float* __restrict__ resp,
    double* __restrict__ dS, double* __restrict__ dSS,
    float* __restrict__ fM, unsigned* __restrict__ uI,
    unsigned* __restrict__ uC)
{
    const int b = blockIdx.y;
    const float4* __restrict__ base =
        reinterpret_cast<const float4*>(resp) + (size_t)b * NVEC;
    const unsigned tid = blockIdx.x * TPB + threadIdx.x;

    float fsum = 0.f, fss = 0.f;
    float bv = -INFINITY;
    unsigned bi = 0;
    unsigned long long cnt = 0;   // wave-uniform (ballot-accumulated)

    #pragma unroll
    for (int i = 0; i < NITER; ++i) {
        const unsigned v = tid + (unsigned)i * STRIDE;
        float4 x = base[v];

        // sums over positives (relu): 3 VALU/elt
        float r;
        r = fmaxf(x.x, 0.f); fsum += r; fss = fmaf(r, r, fss);
        r = fmaxf(x.y, 0.f); fsum += r; fss = fmaf(r, r, fss);
        r = fmaxf(x.z, 0.f); fsum += r; fss = fmaf(r, r, fss);
        r = fmaxf(x.w, 0.f); fsum += r; fss = fmaf(r, r, fss);

        // positive count: 1 v_cmp + scalar bcnt per element
        cnt += __popcll(__ballot(x.x > 0.f));
        cnt += __popcll(__ballot(x.y > 0.f));
        cnt += __popcll(__ballot(x.z > 0.f));
        cnt += __popcll(__ballot(x.w > 0.f));

        // running max: fmax tree + rare branch for the index.
        // In-thread indices ascend, so strict > keeps the earliest (jnp rule).
        const float m01 = fmaxf(x.x, x.y);
        const float m23 = fmaxf(x.z, x.w);
        const float m4  = fmaxf(m01, m23);
        if (m4 > bv) {
            bv = m4;
            const unsigned e0 = v * 4u;
            bi = (x.x == m4) ? e0
               : (x.y == m4) ? e0 + 1u
               : (x.z == m4) ? e0 + 2u
               : e0 + 3u;
        }
    }

    double ds = (double)fsum, dss = (double)fss;
    // wave(64) reduce — cnt is already wave-uniform (ballot), don't shuffle it
    for (int off = 32; off > 0; off >>= 1) {
        ds  += __shfl_down(ds,  off, 64);
        dss += __shfl_down(dss, off, 64);
        float    ov = __shfl_down(bv, off, 64);
        unsigned oi = __shfl_down(bi, off, 64);
        argmax_combine(bv, bi, ov, oi);
    }

    __shared__ double sds[4], sdss[4];
    __shared__ float  sbv[4];
    __shared__ unsigned sbi[4], scnt[4];
    const int wave = threadIdx.x >> 6;
    const int lane = threadIdx.x & 63;
    if (lane == 0) {
        sds[wave] = ds; sdss[wave] = dss;
        sbv[wave] = bv; sbi[wave] = bi; scnt[wave] = (unsigned)cnt;
    }
    __syncthreads();
    if (threadIdx.x == 0) {
        unsigned ctot = scnt[0];
        for (int w = 1; w < 4; ++w) {
            ds += sds[w]; dss += sdss[w]; ctot += scnt[w];
            argmax_combine(bv, bi, sbv[w], sbi[w]);
        }
        const unsigned p = (unsigned)b * NBLK + blockIdx.x;
        dS[p] = ds; dSS[p] = dss; fM[p] = bv; uI[p] = bi; uC[p] = ctot;
    }
}

// Pass 2 (fused with final average): ONE block, 256 threads.
// Wave w handles batches w and w+4 entirely wave-locally (no barriers in the
// reduction), then thread 0 averages the 8 psr values.
__global__ __launch_bounds__(TPB) void psr_pass2(
    const float* __restrict__ resp,
    const double* __restrict__ dS, const double* __restrict__ dSS,
    const float* __restrict__ fM, const unsigned* __restrict__ uI,
    const unsigned* __restrict__ uC,
    float* __restrict__ out)
{
    const int t = threadIdx.x;
    const int wave = t >> 6;
    const int lane = t & 63;
    __shared__ double s_psr[BB];

    for (int rep = 0; rep < 2; ++rep) {
        const int b = wave + rep * 4;

        double ds = 0.0, dss = 0.0, dcnt = 0.0;
        float bv = -INFINITY;
        unsigned bi = 0xFFFFFFFFu;
        #pragma unroll
        for (int c = 0; c < NBLK / 64; ++c) {
            const unsigned p = (unsigned)b * NBLK + (unsigned)(c * 64 + lane);
            ds   += dS[p];
            dss  += dSS[p];
            dcnt += (double)uC[p];
            argmax_combine(bv, bi, fM[p], uI[p]);
        }
        for (int off = 32; off > 0; off >>= 1) {
            ds   += __shfl_down(ds,   off, 64);
            dss  += __shfl_down(dss,  off, 64);
            dcnt += __shfl_down(dcnt, off, 64);
            float    ov = __shfl_down(bv, off, 64);
            unsigned oi = __shfl_down(bi, off, 64);
            argmax_combine(bv, bi, ov, oi);
        }
        // broadcast argmax index to the whole wave for the window pass
        const unsigned idx = (unsigned)__shfl((int)bi, 0, 64);
        const int cy = (int)(idx >> 11);
        const int cx = (int)(idx & 2047u);

        // 11x11 exclusion window: subtract its positive contribution
        double wsum = 0.0, wss = 0.0, wcnt = 0.0;
        for (int k = lane; k < 121; k += 64) {
            const int dy = k / 11 - 5;
            const int dx = k % 11 - 5;
            const int y = cy + dy, x = cx + dx;
            if (y >= 0 && y < HH && x >= 0 && x < WW) {
                const float v = resp[(size_t)b * NPB + (size_t)y * WW + (size_t)x];
                if (v > 0.f) {
                    wsum += (double)v;
                    wss  += (double)v * (double)v;
                    wcnt += 1.0;
                }
            }
        }
        for (int off = 32; off > 0; off >>= 1) {
            wsum += __shfl_down(wsum, off, 64);
            wss  += __shfl_down(wss,  off, 64);
            wcnt += __shfl_down(wcnt, off, 64);
        }

        if (lane == 0) {
            const double S  = ds  - wsum;
            const double SS = dss - wss;
            const double N  = dcnt - wcnt;
            const double mean = S / N;
            const double var  = (SS - N * mean * mean) / (N - 1.0);
            s_psr[b] = ((double)bv - mean) / (sqrt(var) + 1e-5);
        }
    }
    __syncthreads();
    if (t == 0) {
        double a = 0.0;
        for (int b2 = 0; b2 < BB; ++b2) a += s_psr[b2];
        out[0] = (float)(a / BB);
    }
}

extern "C" void kernel_launch(void* const* d_in, const int* in_sizes, int n_in,
                              void* d_out, int out_size, void* d_ws, size_t ws_size,
                              hipStream_t stream) {
    const float* resp = (const float*)d_in[0];
    float* out = (float*)d_out;

    char* ws = (char*)d_ws;
    // layout: [dS: 2048 dbl][dSS: 2048 dbl][fM: 2048 f32][uI: 2048 u32][uC: 2048 u32]
    double*   dS  = (double*)(ws);
    double*   dSS = (double*)(ws + 16384);
    float*    fM  = (float*)(ws + 32768);
    unsigned* uI  = (unsigned*)(ws + 40960);
    unsigned* uC  = (unsigned*)(ws + 49152);

    dim3 g1(NBLK, BB);
    psr_pass1<<<g1, TPB, 0, stream>>>(resp, dS, dSS, fM, uI, uC);
    psr_pass2<<<1, TPB, 0, stream>>>(resp, dS, dSS, fM, uI, uC, out);
}